// Round 4
// baseline (2064.860 us; speedup 1.0000x reference)
//
#include <hip/hip_runtime.h>
#include <math.h>

// ---------------------------------------------------------------------------
// SheafDiffusion on MI355X — round 3: fp32 I/O (bf16 hypothesis falsified by
// NaN), fix k_out partial-LDS-fill bug (sW[256..319] were stale residue).
// ---------------------------------------------------------------------------

__device__ __forceinline__ float gelu_tanh(float x) {
    // jax.nn.gelu(approximate=True)
    float x3 = x * x * x;
    float t = tanhf(0.7978845608028654f * (x + 0.044715f * x3));
    return 0.5f * x * (1.0f + t);
}

// Detect whether the edge buffer is int64 (odd int32 words all zero) or int32.
__global__ void k_detect(const int* __restrict__ ei, int* __restrict__ flag) {
    if (blockIdx.x == 0 && threadIdx.x == 0) {
        int is64 = 1;
        for (int i = 1; i < 256; i += 2)
            if (ei[i] != 0) { is64 = 0; break; }
        *flag = is64;
    }
}

__global__ void k_convert(const int* __restrict__ ei, const int* __restrict__ flag,
                          int* __restrict__ src, int* __restrict__ dst, int e) {
    int i = blockIdx.x * blockDim.x + threadIdx.x;
    if (i >= e) return;
    if (*flag) {
        src[i] = ei[2 * i];
        dst[i] = ei[2 * (e + i)];
    } else {
        src[i] = ei[i];
        dst[i] = ei[e + i];
    }
}

// h = x @ W_in + b_in   (N,128)@(128,32)
__global__ void k_embed_h(const float* __restrict__ x, const float* __restrict__ W_in,
                          const float* __restrict__ b_in, float* __restrict__ h, int n) {
    __shared__ float sW[128 * 32];
    __shared__ float sb[32];
    for (int i = threadIdx.x; i < 128 * 32; i += blockDim.x) sW[i] = W_in[i];
    for (int i = threadIdx.x; i < 32; i += blockDim.x) sb[i] = b_in[i];
    __syncthreads();
    int node = blockIdx.x * blockDim.x + threadIdx.x;
    if (node >= n) return;
    float acc[32];
#pragma unroll
    for (int j = 0; j < 32; j++) acc[j] = sb[j];
    const float* xr = x + (size_t)node * 128;
    for (int k = 0; k < 128; k++) {
        float xv = xr[k];
#pragma unroll
        for (int j = 0; j < 32; j++) acc[j] += xv * sW[k * 32 + j];
    }
    float* hr = h + (size_t)node * 32;
#pragma unroll
    for (int j = 0; j < 32; j++) hr[j] = acc[j];
}

// m = gelu(h @ emb1_W + emb1_b)   (N,32)@(32,64)
__global__ void k_embed_m(const float* __restrict__ h, const float* __restrict__ W,
                          const float* __restrict__ b, float* __restrict__ m, int n) {
    __shared__ float sW[32 * 64];
    __shared__ float sb[64];
    for (int i = threadIdx.x; i < 32 * 64; i += blockDim.x) sW[i] = W[i];
    for (int i = threadIdx.x; i < 64; i += blockDim.x) sb[i] = b[i];
    __syncthreads();
    int node = blockIdx.x * blockDim.x + threadIdx.x;
    if (node >= n) return;
    float hr[32];
    const float4* h4 = (const float4*)(h + (size_t)node * 32);
#pragma unroll
    for (int i = 0; i < 8; i++) {
        float4 v = h4[i];
        hr[4 * i] = v.x; hr[4 * i + 1] = v.y; hr[4 * i + 2] = v.z; hr[4 * i + 3] = v.w;
    }
    float* mr = m + (size_t)node * 64;
    for (int j = 0; j < 64; j++) {
        float acc = sb[j];
#pragma unroll
        for (int k = 0; k < 32; k++) acc += hr[k] * sW[k * 64 + j];
        mr[j] = gelu_tanh(acc);
    }
}

// deg[dst] += 1 per edge
__global__ void k_deg(const int* __restrict__ dst, float* __restrict__ deg, int e) {
    int i = blockIdx.x * blockDim.x + threadIdx.x;
    if (i < e) atomicAdd(&deg[dst[i]], 1.0f);
}

// agg[dst] += m[src]  (64 floats/edge, one thread per (edge,feature))
__global__ void k_scatter64(const int* __restrict__ src, const int* __restrict__ dst,
                            const float* __restrict__ m, float* __restrict__ agg, int e) {
    int tid = blockIdx.x * blockDim.x + threadIdx.x;
    int eidx = tid >> 6;
    int f = tid & 63;
    if (eidx >= e) return;
    int s = src[eidx], d = dst[eidx];
    atomicAdd(&agg[(size_t)d * 64 + f], m[(size_t)s * 64 + f]);
}

// m_out = gelu(m_in @ Ws + agg @ Wn); m_in/m_out alias — not __restrict__.
__global__ void k_gnn(const float* m_in, const float* __restrict__ agg,
                      const float* __restrict__ Ws, const float* __restrict__ Wn,
                      float* m_out, int n) {
    __shared__ float sWs[64 * 64];
    __shared__ float sWn[64 * 64];
    for (int i = threadIdx.x; i < 64 * 64; i += blockDim.x) {
        sWs[i] = Ws[i];
        sWn[i] = Wn[i];
    }
    __syncthreads();
    int node = blockIdx.x * blockDim.x + threadIdx.x;
    if (node >= n) return;
    float mr[64], ar[64];
    const float4* m4 = (const float4*)(m_in + (size_t)node * 64);
    const float4* a4 = (const float4*)(agg + (size_t)node * 64);
#pragma unroll
    for (int i = 0; i < 16; i++) {
        float4 v = m4[i];
        mr[4 * i] = v.x; mr[4 * i + 1] = v.y; mr[4 * i + 2] = v.z; mr[4 * i + 3] = v.w;
        float4 w = a4[i];
        ar[4 * i] = w.x; ar[4 * i + 1] = w.y; ar[4 * i + 2] = w.z; ar[4 * i + 3] = w.w;
    }
    float out[64];
    for (int j = 0; j < 64; j++) {
        float acc = 0.0f;
#pragma unroll
        for (int k = 0; k < 64; k++) acc += mr[k] * sWs[k * 64 + j] + ar[k] * sWn[k * 64 + j];
        out[j] = gelu_tanh(acc);
    }
    float* outr = m_out + (size_t)node * 64;
#pragma unroll
    for (int j = 0; j < 64; j++) outr[j] = out[j];
}

// theta -> per-node (cos, sin, rsqrt(deg+1), 0)
__global__ void k_params(const float* __restrict__ m, const float* __restrict__ w2,
                         const float* __restrict__ b2, const float* __restrict__ deg,
                         float4* __restrict__ params, int n) {
    __shared__ float sw[64];
    for (int i = threadIdx.x; i < 64; i += blockDim.x) sw[i] = w2[i];
    __syncthreads();
    int node = blockIdx.x * blockDim.x + threadIdx.x;
    if (node >= n) return;
    float acc = b2[0];
    const float* mr = m + (size_t)node * 64;
#pragma unroll
    for (int k = 0; k < 64; k++) acc += mr[k] * sw[k];
    float theta = tanhf(acc);
    float ang = 6.283185307179586f * theta;
    float c = cosf(ang), s = sinf(ang);
    float rd = rsqrtf(deg[node] + 1.0f);
    params[node] = make_float4(c, s, rd, 0.0f);
}

// aggx[dst] += norm * (R(th_s - th_d) @ xs[src])   one thread per (edge, d*16+h)
__global__ void k_diffuse(const int* __restrict__ src, const int* __restrict__ dst,
                          const float* __restrict__ xs, const float4* __restrict__ params,
                          float* __restrict__ aggx, int e) {
    int tid = blockIdx.x * blockDim.x + threadIdx.x;
    int eidx = tid >> 5;
    int f = tid & 31;
    if (eidx >= e) return;
    int s = src[eidx], d = dst[eidx];
    float4 ps = params[s];
    float4 pd = params[d];
    float cd = pd.x * ps.x + pd.y * ps.y;     // cos(th_s - th_d)
    float sd = ps.y * pd.x - ps.x * pd.y;     // sin(th_s - th_d)
    float nrm = ps.z * pd.z;
    int hh = f & 15;
    float x0 = xs[(size_t)s * 32 + hh];
    float x1 = xs[(size_t)s * 32 + 16 + hh];
    float val = (f < 16) ? (cd * x0 - sd * x1) : (sd * x0 + cd * x1);
    atomicAdd(&aggx[(size_t)d * 32 + f], val * nrm);
}

// xs = xs - gelu((xs - aggx) @ Wd)   per node; Wd (16,16)
__global__ void k_update(float* __restrict__ xs, const float* __restrict__ aggx,
                         const float* __restrict__ Wd, int n) {
    __shared__ float sW[256];
    for (int i = threadIdx.x; i < 256; i += blockDim.x) sW[i] = Wd[i];
    __syncthreads();
    int node = blockIdx.x * blockDim.x + threadIdx.x;
    if (node >= n) return;
    float xr[32], lx[32];
    float* xrow = xs + (size_t)node * 32;
    const float* arow = aggx + (size_t)node * 32;
#pragma unroll
    for (int i = 0; i < 32; i++) {
        xr[i] = xrow[i];
        lx[i] = xr[i] - arow[i];
    }
#pragma unroll
    for (int dd = 0; dd < 2; dd++) {
        for (int j = 0; j < 16; j++) {
            float acc = 0.0f;
#pragma unroll
            for (int k = 0; k < 16; k++) acc += lx[dd * 16 + k] * sW[k * 16 + j];
            xrow[dd * 16 + j] = xr[dd * 16 + j] - gelu_tanh(acc);
        }
    }
}

// out = xs @ W_out + b_out   (N,32)@(32,10)
__global__ void k_out(const float* __restrict__ xs, const float* __restrict__ W,
                      const float* __restrict__ b, float* __restrict__ out, int n) {
    __shared__ float sW[320];
    __shared__ float sb[10];
    // FIX: strided fill — previous `if (threadIdx.x < 320)` with 256 threads
    // left sW[256..319] as stale LDS residue (the round-0/1 absmax 5.27).
    for (int i = threadIdx.x; i < 320; i += blockDim.x) sW[i] = W[i];
    for (int i = threadIdx.x; i < 10; i += blockDim.x) sb[i] = b[i];
    __syncthreads();
    int node = blockIdx.x * blockDim.x + threadIdx.x;
    if (node >= n) return;
    float xr[32];
    const float4* x4 = (const float4*)(xs + (size_t)node * 32);
#pragma unroll
    for (int i = 0; i < 8; i++) {
        float4 v = x4[i];
        xr[4 * i] = v.x; xr[4 * i + 1] = v.y; xr[4 * i + 2] = v.z; xr[4 * i + 3] = v.w;
    }
    float* orow = out + (size_t)node * 10;
#pragma unroll
    for (int j = 0; j < 10; j++) {
        float acc = sb[j];
#pragma unroll
        for (int k = 0; k < 32; k++) acc += xr[k] * sW[k * 10 + j];
        orow[j] = acc;
    }
}

extern "C" void kernel_launch(void* const* d_in, const int* in_sizes, int n_in,
                              void* d_out, int out_size, void* d_ws, size_t ws_size,
                              hipStream_t stream) {
    const float* x      = (const float*)d_in[0];
    const int*   ei     = (const int*)d_in[1];
    const float* W_in   = (const float*)d_in[2];
    const float* b_in   = (const float*)d_in[3];
    const float* emb1_W = (const float*)d_in[4];
    const float* emb1_b = (const float*)d_in[5];
    const float* Ws1    = (const float*)d_in[6];
    const float* Wn1    = (const float*)d_in[7];
    const float* Ws2    = (const float*)d_in[8];
    const float* Wn2    = (const float*)d_in[9];
    const float* emb2_W = (const float*)d_in[10];
    const float* emb2_b = (const float*)d_in[11];
    const float* W_diff = (const float*)d_in[12];
    const float* W_out  = (const float*)d_in[13];
    const float* b_out  = (const float*)d_in[14];

    int n = in_sizes[0] / 128;  // 100000
    int e = in_sizes[1] / 2;    // 1600000

    // ---- workspace layout ----
    char* wsb = (char*)d_ws;
    int*    src    = (int*)wsb;                          wsb += (size_t)e * 4;
    int*    dst    = (int*)wsb;                          wsb += (size_t)e * 4;
    int*    flag   = (int*)wsb;                          wsb += 16;
    float*  h      = (float*)wsb;                        wsb += (size_t)n * 32 * 4;
    float*  m      = (float*)wsb;                        wsb += (size_t)n * 64 * 4;
    float*  agg    = (float*)wsb;                        wsb += (size_t)n * 64 * 4;
    float*  deg    = (float*)wsb;                        wsb += (size_t)n * 4;
    float4* params = (float4*)wsb;

    int nb = (n + 255) / 256;
    int eb = (e + 255) / 256;

    k_detect<<<1, 64, 0, stream>>>(ei, flag);
    k_convert<<<eb, 256, 0, stream>>>(ei, flag, src, dst, e);

    hipMemsetAsync(deg, 0, (size_t)n * sizeof(float), stream);
    hipMemsetAsync(agg, 0, (size_t)n * 64 * sizeof(float), stream);

    k_embed_h<<<nb, 256, 0, stream>>>(x, W_in, b_in, h, n);
    k_embed_m<<<nb, 256, 0, stream>>>(h, emb1_W, emb1_b, m, n);
    k_deg<<<eb, 256, 0, stream>>>(dst, deg, e);

    int sb64 = (int)(((size_t)e * 64 + 255) / 256);
    k_scatter64<<<sb64, 256, 0, stream>>>(src, dst, m, agg, e);
    k_gnn<<<nb, 256, 0, stream>>>(m, agg, Ws1, Wn1, m, n);

    hipMemsetAsync(agg, 0, (size_t)n * 64 * sizeof(float), stream);
    k_scatter64<<<sb64, 256, 0, stream>>>(src, dst, m, agg, e);
    k_gnn<<<nb, 256, 0, stream>>>(m, agg, Ws2, Wn2, m, n);

    k_params<<<nb, 256, 0, stream>>>(m, emb2_W, emb2_b, deg, params, n);

    int sb32 = (int)(((size_t)e * 32 + 255) / 256);
    for (int l = 0; l < 2; l++) {
        hipMemsetAsync(agg, 0, (size_t)n * 32 * sizeof(float), stream);
        k_diffuse<<<sb32, 256, 0, stream>>>(src, dst, h, params, agg, e);
        k_update<<<nb, 256, 0, stream>>>(h, agg, W_diff + (size_t)l * 256, n);
    }

    k_out<<<nb, 256, 0, stream>>>(h, W_out, b_out, (float*)d_out, n);
}

// Round 5
// 1215.926 us; speedup vs baseline: 1.6982x; 1.6982x over previous
//
#include <hip/hip_runtime.h>
#include <math.h>

// ---------------------------------------------------------------------------
// SheafDiffusion on MI355X — round 4: replace atomic scatter with CSR gather.
// CSR (by dst) built on-device each launch: histogram -> tile scan -> fill.
// Aggregations become per-node register gathers (no atomics, 1 store/node).
// ---------------------------------------------------------------------------

__device__ __forceinline__ float gelu_tanh(float x) {
    float x3 = x * x * x;
    float t = tanhf(0.7978845608028654f * (x + 0.044715f * x3));
    return 0.5f * x * (1.0f + t);
}

// ---- edge dtype handling -------------------------------------------------
__global__ void k_detect(const int* __restrict__ ei, int* __restrict__ flag) {
    if (blockIdx.x == 0 && threadIdx.x == 0) {
        int is64 = 1;
        for (int i = 1; i < 256; i += 2)
            if (ei[i] != 0) { is64 = 0; break; }
        *flag = is64;
    }
}

__global__ void k_convert(const int* __restrict__ ei, const int* __restrict__ flag,
                          int* __restrict__ src, int* __restrict__ dst, int e) {
    int i = blockIdx.x * blockDim.x + threadIdx.x;
    if (i >= e) return;
    if (*flag) {
        src[i] = ei[2 * i];
        dst[i] = ei[2 * (e + i)];
    } else {
        src[i] = ei[i];
        dst[i] = ei[e + i];
    }
}

// ---- CSR build -----------------------------------------------------------
__global__ void k_hist(const int* __restrict__ dst, int* __restrict__ cnt, int e) {
    int i = blockIdx.x * blockDim.x + threadIdx.x;
    if (i < e) atomicAdd(&cnt[dst[i]], 1);
}

// inclusive scan of 256-tiles; writes incl value to row_ptr[i+1], tile total to bs
__global__ void k_scan1(const int* __restrict__ cnt, int* __restrict__ row_ptr,
                        int* __restrict__ bs, int n) {
    __shared__ int s[256];
    int i = blockIdx.x * 256 + threadIdx.x;
    int v = (i < n) ? cnt[i] : 0;
    s[threadIdx.x] = v;
    __syncthreads();
#pragma unroll
    for (int off = 1; off < 256; off <<= 1) {
        int add = (threadIdx.x >= off) ? s[threadIdx.x - off] : 0;
        __syncthreads();
        s[threadIdx.x] += add;
        __syncthreads();
    }
    if (i < n) row_ptr[i + 1] = s[threadIdx.x];
    if (threadIdx.x == 255) bs[blockIdx.x] = s[255];
}

// exclusive scan of tile sums (single block, up to 1024 tiles)
__global__ void k_scan2(int* __restrict__ bs, int nt) {
    __shared__ int s[1024];
    int t = threadIdx.x;
    s[t] = (t < nt) ? bs[t] : 0;
    __syncthreads();
#pragma unroll
    for (int off = 1; off < 1024; off <<= 1) {
        int add = (t >= off) ? s[t - off] : 0;
        __syncthreads();
        s[t] += add;
        __syncthreads();
    }
    if (t < nt) bs[t] = (t == 0) ? 0 : s[t - 1];
}

__global__ void k_scan3(int* __restrict__ row_ptr, const int* __restrict__ bs, int n) {
    int i = blockIdx.x * 256 + threadIdx.x;
    if (i < n) row_ptr[i + 1] += bs[blockIdx.x];
    if (i == 0) row_ptr[0] = 0;
}

__global__ void k_copy(const int* __restrict__ row_ptr, int* __restrict__ cursor, int n) {
    int i = blockIdx.x * blockDim.x + threadIdx.x;
    if (i < n) cursor[i] = row_ptr[i];
}

__global__ void k_fill(const int* __restrict__ src, const int* __restrict__ dst,
                       int* __restrict__ cursor, int* __restrict__ csr_src, int e) {
    int i = blockIdx.x * blockDim.x + threadIdx.x;
    if (i >= e) return;
    int d = dst[i];
    int pos = atomicAdd(&cursor[d], 1);
    csr_src[pos] = src[i];
}

// ---- dense per-node kernels ---------------------------------------------
__global__ void k_embed_h(const float* __restrict__ x, const float* __restrict__ W_in,
                          const float* __restrict__ b_in, float* __restrict__ h, int n) {
    __shared__ float sW[128 * 32];
    __shared__ float sb[32];
    for (int i = threadIdx.x; i < 128 * 32; i += blockDim.x) sW[i] = W_in[i];
    for (int i = threadIdx.x; i < 32; i += blockDim.x) sb[i] = b_in[i];
    __syncthreads();
    int node = blockIdx.x * blockDim.x + threadIdx.x;
    if (node >= n) return;
    float acc[32];
#pragma unroll
    for (int j = 0; j < 32; j++) acc[j] = sb[j];
    const float* xr = x + (size_t)node * 128;
    for (int k = 0; k < 128; k++) {
        float xv = xr[k];
#pragma unroll
        for (int j = 0; j < 32; j++) acc[j] += xv * sW[k * 32 + j];
    }
    float* hr = h + (size_t)node * 32;
#pragma unroll
    for (int j = 0; j < 32; j++) hr[j] = acc[j];
}

__global__ void k_embed_m(const float* __restrict__ h, const float* __restrict__ W,
                          const float* __restrict__ b, float* __restrict__ m, int n) {
    __shared__ float sW[32 * 64];
    __shared__ float sb[64];
    for (int i = threadIdx.x; i < 32 * 64; i += blockDim.x) sW[i] = W[i];
    for (int i = threadIdx.x; i < 64; i += blockDim.x) sb[i] = b[i];
    __syncthreads();
    int node = blockIdx.x * blockDim.x + threadIdx.x;
    if (node >= n) return;
    float hr[32];
    const float4* h4 = (const float4*)(h + (size_t)node * 32);
#pragma unroll
    for (int i = 0; i < 8; i++) {
        float4 v = h4[i];
        hr[4 * i] = v.x; hr[4 * i + 1] = v.y; hr[4 * i + 2] = v.z; hr[4 * i + 3] = v.w;
    }
    float* mr = m + (size_t)node * 64;
    for (int j = 0; j < 64; j++) {
        float acc = sb[j];
#pragma unroll
        for (int k = 0; k < 32; k++) acc += hr[k] * sW[k * 64 + j];
        mr[j] = gelu_tanh(acc);
    }
}

// agg[node] = sum over in-edges of m[src]   (one wave per node, 64 lanes = 64 feats)
__global__ void k_gather64(const int* __restrict__ row_ptr, const int* __restrict__ csr_src,
                           const float* __restrict__ m, float* __restrict__ agg, int n) {
    int wave = (blockIdx.x * blockDim.x + threadIdx.x) >> 6;
    int f = threadIdx.x & 63;
    if (wave >= n) return;
    int beg = row_ptr[wave], end = row_ptr[wave + 1];
    float acc = 0.0f;
    int p = beg;
    for (; p + 1 < end; p += 2) {
        int s0 = csr_src[p], s1 = csr_src[p + 1];
        float a = m[(size_t)s0 * 64 + f];
        float b = m[(size_t)s1 * 64 + f];
        acc += a + b;
    }
    if (p < end) acc += m[(size_t)csr_src[p] * 64 + f];
    agg[(size_t)wave * 64 + f] = acc;
}

// m_out = gelu(m_in @ Ws + agg @ Wn); aliasing allowed
__global__ void k_gnn(const float* m_in, const float* __restrict__ agg,
                      const float* __restrict__ Ws, const float* __restrict__ Wn,
                      float* m_out, int n) {
    __shared__ float sWs[64 * 64];
    __shared__ float sWn[64 * 64];
    for (int i = threadIdx.x; i < 64 * 64; i += blockDim.x) {
        sWs[i] = Ws[i];
        sWn[i] = Wn[i];
    }
    __syncthreads();
    int node = blockIdx.x * blockDim.x + threadIdx.x;
    if (node >= n) return;
    float mr[64], ar[64];
    const float4* m4 = (const float4*)(m_in + (size_t)node * 64);
    const float4* a4 = (const float4*)(agg + (size_t)node * 64);
#pragma unroll
    for (int i = 0; i < 16; i++) {
        float4 v = m4[i];
        mr[4 * i] = v.x; mr[4 * i + 1] = v.y; mr[4 * i + 2] = v.z; mr[4 * i + 3] = v.w;
        float4 w = a4[i];
        ar[4 * i] = w.x; ar[4 * i + 1] = w.y; ar[4 * i + 2] = w.z; ar[4 * i + 3] = w.w;
    }
    float out[64];
    for (int j = 0; j < 64; j++) {
        float acc = 0.0f;
#pragma unroll
        for (int k = 0; k < 64; k++) acc += mr[k] * sWs[k * 64 + j] + ar[k] * sWn[k * 64 + j];
        out[j] = gelu_tanh(acc);
    }
    float* outr = m_out + (size_t)node * 64;
#pragma unroll
    for (int j = 0; j < 64; j++) outr[j] = out[j];
}

// theta -> per-node (cos, sin, rsqrt(deg+1), 0); deg from CSR row_ptr
__global__ void k_params(const float* __restrict__ m, const float* __restrict__ w2,
                         const float* __restrict__ b2, const int* __restrict__ row_ptr,
                         float4* __restrict__ params, int n) {
    __shared__ float sw[64];
    for (int i = threadIdx.x; i < 64; i += blockDim.x) sw[i] = w2[i];
    __syncthreads();
    int node = blockIdx.x * blockDim.x + threadIdx.x;
    if (node >= n) return;
    float acc = b2[0];
    const float* mr = m + (size_t)node * 64;
#pragma unroll
    for (int k = 0; k < 64; k++) acc += mr[k] * sw[k];
    float theta = tanhf(acc);
    float ang = 6.283185307179586f * theta;
    float c = cosf(ang), s = sinf(ang);
    float deg = (float)(row_ptr[node + 1] - row_ptr[node]);
    float rd = rsqrtf(deg + 1.0f);
    params[node] = make_float4(c, s, rd, 0.0f);
}

// aggx[node] = sum_e norm_e * R(th_s - th_d) @ xs[src]   (32 lanes per node)
__global__ void k_gather_diffuse(const int* __restrict__ row_ptr, const int* __restrict__ csr_src,
                                 const float* __restrict__ xs, const float4* __restrict__ params,
                                 float* __restrict__ aggx, int n) {
    int tid = blockIdx.x * blockDim.x + threadIdx.x;
    int node = tid >> 5;
    int f = tid & 31;
    if (node >= n) return;
    float4 pd = params[node];
    int beg = row_ptr[node], end = row_ptr[node + 1];
    float acc = 0.0f;
    bool lo = (f < 16);
    for (int p = beg; p < end; ++p) {
        int s = csr_src[p];
        float4 ps = params[s];
        float cd = pd.x * ps.x + pd.y * ps.y;   // cos(th_s - th_d)
        float sd = ps.y * pd.x - ps.x * pd.y;   // sin(th_s - th_d)
        float nrm = ps.z * pd.z;
        float x_own = xs[(size_t)s * 32 + f];
        float x_part = __shfl_xor(x_own, 16, 64);   // partner feature (f^16), same 32-group
        float val = lo ? (cd * x_own - sd * x_part) : (sd * x_part + cd * x_own);
        acc += nrm * val;
    }
    aggx[(size_t)node * 32 + f] = acc;
}

// xs = xs - gelu((xs - aggx) @ Wd)
__global__ void k_update(float* __restrict__ xs, const float* __restrict__ aggx,
                         const float* __restrict__ Wd, int n) {
    __shared__ float sW[256];
    for (int i = threadIdx.x; i < 256; i += blockDim.x) sW[i] = Wd[i];
    __syncthreads();
    int node = blockIdx.x * blockDim.x + threadIdx.x;
    if (node >= n) return;
    float xr[32], lx[32];
    float* xrow = xs + (size_t)node * 32;
    const float* arow = aggx + (size_t)node * 32;
#pragma unroll
    for (int i = 0; i < 32; i++) {
        xr[i] = xrow[i];
        lx[i] = xr[i] - arow[i];
    }
#pragma unroll
    for (int dd = 0; dd < 2; dd++) {
        for (int j = 0; j < 16; j++) {
            float acc = 0.0f;
#pragma unroll
            for (int k = 0; k < 16; k++) acc += lx[dd * 16 + k] * sW[k * 16 + j];
            xrow[dd * 16 + j] = xr[dd * 16 + j] - gelu_tanh(acc);
        }
    }
}

__global__ void k_out(const float* __restrict__ xs, const float* __restrict__ W,
                      const float* __restrict__ b, float* __restrict__ out, int n) {
    __shared__ float sW[320];
    __shared__ float sb[10];
    for (int i = threadIdx.x; i < 320; i += blockDim.x) sW[i] = W[i];
    for (int i = threadIdx.x; i < 10; i += blockDim.x) sb[i] = b[i];
    __syncthreads();
    int node = blockIdx.x * blockDim.x + threadIdx.x;
    if (node >= n) return;
    float xr[32];
    const float4* x4 = (const float4*)(xs + (size_t)node * 32);
#pragma unroll
    for (int i = 0; i < 8; i++) {
        float4 v = x4[i];
        xr[4 * i] = v.x; xr[4 * i + 1] = v.y; xr[4 * i + 2] = v.z; xr[4 * i + 3] = v.w;
    }
    float* orow = out + (size_t)node * 10;
#pragma unroll
    for (int j = 0; j < 10; j++) {
        float acc = sb[j];
#pragma unroll
        for (int k = 0; k < 32; k++) acc += xr[k] * sW[k * 10 + j];
        orow[j] = acc;
    }
}

static inline size_t align256(size_t x) { return (x + 255) & ~(size_t)255; }

extern "C" void kernel_launch(void* const* d_in, const int* in_sizes, int n_in,
                              void* d_out, int out_size, void* d_ws, size_t ws_size,
                              hipStream_t stream) {
    const float* x      = (const float*)d_in[0];
    const int*   ei     = (const int*)d_in[1];
    const float* W_in   = (const float*)d_in[2];
    const float* b_in   = (const float*)d_in[3];
    const float* emb1_W = (const float*)d_in[4];
    const float* emb1_b = (const float*)d_in[5];
    const float* Ws1    = (const float*)d_in[6];
    const float* Wn1    = (const float*)d_in[7];
    const float* Ws2    = (const float*)d_in[8];
    const float* Wn2    = (const float*)d_in[9];
    const float* emb2_W = (const float*)d_in[10];
    const float* emb2_b = (const float*)d_in[11];
    const float* W_diff = (const float*)d_in[12];
    const float* W_out  = (const float*)d_in[13];
    const float* b_out  = (const float*)d_in[14];

    int n = in_sizes[0] / 128;  // 100000
    int e = in_sizes[1] / 2;    // 1600000
    int nt = (n + 255) / 256;   // scan tiles (<=1024 supported)

    // ---- workspace layout (256B-aligned sections) ----
    char* base = (char*)d_ws;
    size_t off = 0;
    int* src      = (int*)(base + off); off = align256(off + (size_t)e * 4);
    int* dst      = (int*)(base + off); off = align256(off + (size_t)e * 4);
    int* csr_src  = (int*)(base + off); off = align256(off + (size_t)e * 4);
    int* row_ptr  = (int*)(base + off); off = align256(off + (size_t)(n + 1) * 4);
    int* cursor   = (int*)(base + off); off = align256(off + (size_t)n * 4);
    int* bsums    = (int*)(base + off); off = align256(off + (size_t)nt * 4);
    int* flag     = (int*)(base + off); off = align256(off + 16);
    float*  h     = (float*)(base + off); off = align256(off + (size_t)n * 32 * 4);
    float*  m     = (float*)(base + off); off = align256(off + (size_t)n * 64 * 4);
    float*  agg   = (float*)(base + off); off = align256(off + (size_t)n * 64 * 4);
    float4* params= (float4*)(base + off);

    int nb = (n + 255) / 256;
    int eb = (e + 255) / 256;

    // edge convert + CSR build
    k_detect<<<1, 64, 0, stream>>>(ei, flag);
    k_convert<<<eb, 256, 0, stream>>>(ei, flag, src, dst, e);
    hipMemsetAsync(cursor, 0, (size_t)n * 4, stream);
    k_hist<<<eb, 256, 0, stream>>>(dst, cursor, e);
    k_scan1<<<nt, 256, 0, stream>>>(cursor, row_ptr, bsums, n);
    k_scan2<<<1, 1024, 0, stream>>>(bsums, nt);
    k_scan3<<<nt, 256, 0, stream>>>(row_ptr, bsums, n);
    k_copy<<<nb, 256, 0, stream>>>(row_ptr, cursor, n);
    k_fill<<<eb, 256, 0, stream>>>(src, dst, cursor, csr_src, e);

    // embeddings
    k_embed_h<<<nb, 256, 0, stream>>>(x, W_in, b_in, h, n);
    k_embed_m<<<nb, 256, 0, stream>>>(h, emb1_W, emb1_b, m, n);

    // sheaf learner GNN layers (gather + dense)
    int gb64 = (n * 64 + 255) / 256;       // one wave per node
    k_gather64<<<gb64, 256, 0, stream>>>(row_ptr, csr_src, m, agg, n);
    k_gnn<<<nb, 256, 0, stream>>>(m, agg, Ws1, Wn1, m, n);
    k_gather64<<<gb64, 256, 0, stream>>>(row_ptr, csr_src, m, agg, n);
    k_gnn<<<nb, 256, 0, stream>>>(m, agg, Ws2, Wn2, m, n);

    k_params<<<nb, 256, 0, stream>>>(m, emb2_W, emb2_b, row_ptr, params, n);

    // diffusion layers (gather + update)
    int gb32 = (n * 32 + 255) / 256;       // 32 lanes per node
    for (int l = 0; l < 2; l++) {
        k_gather_diffuse<<<gb32, 256, 0, stream>>>(row_ptr, csr_src, h, params, agg, n);
        k_update<<<nb, 256, 0, stream>>>(h, agg, W_diff + (size_t)l * 256, n);
    }

    k_out<<<nb, 256, 0, stream>>>(h, W_out, b_out, (float*)d_out, n);
}

// Round 6
// 1128.621 us; speedup vs baseline: 1.8295x; 1.0774x over previous
//
#include <hip/hip_runtime.h>
#include <math.h>

// ---------------------------------------------------------------------------
// SheafDiffusion on MI355X — round 5: register-tiled k_gnn (kills scratch
// spills: 64n x 64f tile, 4x4 acc/thread, transposed+padded LDS A-tile),
// float4-broadcast weight reads in k_embed_h/k_embed_m.
// ---------------------------------------------------------------------------

__device__ __forceinline__ float gelu_tanh(float x) {
    float x3 = x * x * x;
    float t = tanhf(0.7978845608028654f * (x + 0.044715f * x3));
    return 0.5f * x * (1.0f + t);
}

// ---- edge dtype handling -------------------------------------------------
__global__ void k_detect(const int* __restrict__ ei, int* __restrict__ flag) {
    if (blockIdx.x == 0 && threadIdx.x == 0) {
        int is64 = 1;
        for (int i = 1; i < 256; i += 2)
            if (ei[i] != 0) { is64 = 0; break; }
        *flag = is64;
    }
}

__global__ void k_convert(const int* __restrict__ ei, const int* __restrict__ flag,
                          int* __restrict__ src, int* __restrict__ dst, int e) {
    int i = blockIdx.x * blockDim.x + threadIdx.x;
    if (i >= e) return;
    if (*flag) {
        src[i] = ei[2 * i];
        dst[i] = ei[2 * (e + i)];
    } else {
        src[i] = ei[i];
        dst[i] = ei[e + i];
    }
}

// ---- CSR build -----------------------------------------------------------
__global__ void k_hist(const int* __restrict__ dst, int* __restrict__ cnt, int e) {
    int i = blockIdx.x * blockDim.x + threadIdx.x;
    if (i < e) atomicAdd(&cnt[dst[i]], 1);
}

__global__ void k_scan1(const int* __restrict__ cnt, int* __restrict__ row_ptr,
                        int* __restrict__ bs, int n) {
    __shared__ int s[256];
    int i = blockIdx.x * 256 + threadIdx.x;
    int v = (i < n) ? cnt[i] : 0;
    s[threadIdx.x] = v;
    __syncthreads();
#pragma unroll
    for (int off = 1; off < 256; off <<= 1) {
        int add = (threadIdx.x >= off) ? s[threadIdx.x - off] : 0;
        __syncthreads();
        s[threadIdx.x] += add;
        __syncthreads();
    }
    if (i < n) row_ptr[i + 1] = s[threadIdx.x];
    if (threadIdx.x == 255) bs[blockIdx.x] = s[255];
}

__global__ void k_scan2(int* __restrict__ bs, int nt) {
    __shared__ int s[1024];
    int t = threadIdx.x;
    s[t] = (t < nt) ? bs[t] : 0;
    __syncthreads();
#pragma unroll
    for (int off = 1; off < 1024; off <<= 1) {
        int add = (t >= off) ? s[t - off] : 0;
        __syncthreads();
        s[t] += add;
        __syncthreads();
    }
    if (t < nt) bs[t] = (t == 0) ? 0 : s[t - 1];
}

__global__ void k_scan3(int* __restrict__ row_ptr, const int* __restrict__ bs, int n) {
    int i = blockIdx.x * 256 + threadIdx.x;
    if (i < n) row_ptr[i + 1] += bs[blockIdx.x];
    if (i == 0) row_ptr[0] = 0;
}

__global__ void k_copy(const int* __restrict__ row_ptr, int* __restrict__ cursor, int n) {
    int i = blockIdx.x * blockDim.x + threadIdx.x;
    if (i < n) cursor[i] = row_ptr[i];
}

__global__ void k_fill(const int* __restrict__ src, const int* __restrict__ dst,
                       int* __restrict__ cursor, int* __restrict__ csr_src, int e) {
    int i = blockIdx.x * blockDim.x + threadIdx.x;
    if (i >= e) return;
    int d = dst[i];
    int pos = atomicAdd(&cursor[d], 1);
    csr_src[pos] = src[i];
}

// ---- dense per-node kernels ---------------------------------------------
// h = x @ W_in + b_in   (N,128)@(128,32); W read as float4 broadcasts
__global__ void k_embed_h(const float* __restrict__ x, const float* __restrict__ W_in,
                          const float* __restrict__ b_in, float* __restrict__ h, int n) {
    __shared__ float4 sW4[128 * 8];   // W[k][j] grouped by 4 features
    __shared__ float sb[32];
    for (int i = threadIdx.x; i < 128 * 8; i += blockDim.x) sW4[i] = ((const float4*)W_in)[i];
    for (int i = threadIdx.x; i < 32; i += blockDim.x) sb[i] = b_in[i];
    __syncthreads();
    int node = blockIdx.x * blockDim.x + threadIdx.x;
    if (node >= n) return;
    float4 acc[8];
#pragma unroll
    for (int jq = 0; jq < 8; jq++)
        acc[jq] = make_float4(sb[4 * jq], sb[4 * jq + 1], sb[4 * jq + 2], sb[4 * jq + 3]);
    const float4* xr = (const float4*)(x + (size_t)node * 128);
    for (int kk = 0; kk < 32; kk++) {
        float4 xv4 = xr[kk];
        float xv[4] = {xv4.x, xv4.y, xv4.z, xv4.w};
#pragma unroll
        for (int t = 0; t < 4; t++) {
            int k = kk * 4 + t;
#pragma unroll
            for (int jq = 0; jq < 8; jq++) {
                float4 w = sW4[k * 8 + jq];
                acc[jq].x += xv[t] * w.x;
                acc[jq].y += xv[t] * w.y;
                acc[jq].z += xv[t] * w.z;
                acc[jq].w += xv[t] * w.w;
            }
        }
    }
    float4* hr = (float4*)(h + (size_t)node * 32);
#pragma unroll
    for (int jq = 0; jq < 8; jq++) hr[jq] = acc[jq];
}

// m = gelu(h @ emb1_W + emb1_b)  (N,32)@(32,64); W as float4 broadcasts
__global__ void k_embed_m(const float* __restrict__ h, const float* __restrict__ W,
                          const float* __restrict__ b, float* __restrict__ m, int n) {
    __shared__ float4 sW4[32 * 16];
    __shared__ float sb[64];
    for (int i = threadIdx.x; i < 32 * 16; i += blockDim.x) sW4[i] = ((const float4*)W)[i];
    for (int i = threadIdx.x; i < 64; i += blockDim.x) sb[i] = b[i];
    __syncthreads();
    int node = blockIdx.x * blockDim.x + threadIdx.x;
    if (node >= n) return;
    float hr[32];
    const float4* h4 = (const float4*)(h + (size_t)node * 32);
#pragma unroll
    for (int i = 0; i < 8; i++) {
        float4 v = h4[i];
        hr[4 * i] = v.x; hr[4 * i + 1] = v.y; hr[4 * i + 2] = v.z; hr[4 * i + 3] = v.w;
    }
    float4* mr = (float4*)(m + (size_t)node * 64);
#pragma unroll 4
    for (int jq = 0; jq < 16; jq++) {
        float4 acc = make_float4(sb[4 * jq], sb[4 * jq + 1], sb[4 * jq + 2], sb[4 * jq + 3]);
#pragma unroll
        for (int k = 0; k < 32; k++) {
            float4 w = sW4[k * 16 + jq];
            acc.x += hr[k] * w.x;
            acc.y += hr[k] * w.y;
            acc.z += hr[k] * w.z;
            acc.w += hr[k] * w.w;
        }
        mr[jq] = make_float4(gelu_tanh(acc.x), gelu_tanh(acc.y), gelu_tanh(acc.z), gelu_tanh(acc.w));
    }
}

// agg[node] = sum over in-edges of m[src]   (one wave per node, 64 lanes = 64 feats)
__global__ void k_gather64(const int* __restrict__ row_ptr, const int* __restrict__ csr_src,
                           const float* __restrict__ m, float* __restrict__ agg, int n) {
    int wave = (blockIdx.x * blockDim.x + threadIdx.x) >> 6;
    int f = threadIdx.x & 63;
    if (wave >= n) return;
    int beg = row_ptr[wave], end = row_ptr[wave + 1];
    float acc = 0.0f;
    int p = beg;
    for (; p + 1 < end; p += 2) {
        int s0 = csr_src[p], s1 = csr_src[p + 1];
        float a = m[(size_t)s0 * 64 + f];
        float b = m[(size_t)s1 * 64 + f];
        acc += a + b;
    }
    if (p < end) acc += m[(size_t)csr_src[p] * 64 + f];
    agg[(size_t)wave * 64 + f] = acc;
}

// m_out = gelu(m_in @ Ws + agg @ Wn) — register-tiled GEMM.
// Block: 64 nodes x 64 feats; thread (tx,ty): 4 feats x 4 nodes; 4x4 acc.
__global__ __launch_bounds__(256) void k_gnn(const float* m_in, const float* __restrict__ agg,
                      const float* __restrict__ Ws, const float* __restrict__ Wn,
                      float* m_out, int n) {
    __shared__ float sWs[64 * 64];
    __shared__ float sWn[64 * 64];
    __shared__ float sA[64 * 68];    // transposed tile [k][node], pad 68 (aligned float4, 2-way banks)
    int tid = threadIdx.x;
    for (int i = tid; i < 64 * 64; i += 256) { sWs[i] = Ws[i]; sWn[i] = Wn[i]; }
    int node0 = blockIdx.x * 64;
    int tx = tid & 15;   // feature quad
    int ty = tid >> 4;   // node quad
    float acc[4][4];
#pragma unroll
    for (int i = 0; i < 4; i++)
#pragma unroll
        for (int j = 0; j < 4; j++) acc[i][j] = 0.0f;

#pragma unroll
    for (int phase = 0; phase < 2; phase++) {
        const float* A = phase ? agg : m_in;
        __syncthreads();
        // stage 64x64 tile transposed: wave reads one row (256B coalesced)
        int r0 = tid >> 6;       // 0..3
        int c = tid & 63;
#pragma unroll
        for (int rr = 0; rr < 16; rr++) {
            int r = rr * 4 + r0;
            int node = node0 + r;
            float v = (node < n) ? A[(size_t)node * 64 + c] : 0.0f;
            sA[c * 68 + r] = v;
        }
        __syncthreads();
        const float* w = phase ? sWn : sWs;
#pragma unroll 4
        for (int k = 0; k < 64; k++) {
            float4 av = *(const float4*)&sA[k * 68 + ty * 4];
            float4 wv = *(const float4*)&w[k * 64 + tx * 4];
            float a_[4] = {av.x, av.y, av.z, av.w};
            float w_[4] = {wv.x, wv.y, wv.z, wv.w};
#pragma unroll
            for (int i = 0; i < 4; i++)
#pragma unroll
                for (int j = 0; j < 4; j++)
                    acc[i][j] += a_[i] * w_[j];
        }
    }
#pragma unroll
    for (int i = 0; i < 4; i++) {
        int node = node0 + ty * 4 + i;
        if (node >= n) continue;
        float4 o;
        o.x = gelu_tanh(acc[i][0]);
        o.y = gelu_tanh(acc[i][1]);
        o.z = gelu_tanh(acc[i][2]);
        o.w = gelu_tanh(acc[i][3]);
        *(float4*)&m_out[(size_t)node * 64 + tx * 4] = o;
    }
}

// theta -> per-node (cos, sin, rsqrt(deg+1), 0); deg from CSR row_ptr
__global__ void k_params(const float* __restrict__ m, const float* __restrict__ w2,
                         const float* __restrict__ b2, const int* __restrict__ row_ptr,
                         float4* __restrict__ params, int n) {
    __shared__ float sw[64];
    for (int i = threadIdx.x; i < 64; i += blockDim.x) sw[i] = w2[i];
    __syncthreads();
    int node = blockIdx.x * blockDim.x + threadIdx.x;
    if (node >= n) return;
    float acc = b2[0];
    const float* mr = m + (size_t)node * 64;
#pragma unroll
    for (int k = 0; k < 64; k++) acc += mr[k] * sw[k];
    float theta = tanhf(acc);
    float ang = 6.283185307179586f * theta;
    float c = cosf(ang), s = sinf(ang);
    float deg = (float)(row_ptr[node + 1] - row_ptr[node]);
    float rd = rsqrtf(deg + 1.0f);
    params[node] = make_float4(c, s, rd, 0.0f);
}

// aggx[node] = sum_e norm_e * R(th_s - th_d) @ xs[src]   (32 lanes per node)
__global__ void k_gather_diffuse(const int* __restrict__ row_ptr, const int* __restrict__ csr_src,
                                 const float* __restrict__ xs, const float4* __restrict__ params,
                                 float* __restrict__ aggx, int n) {
    int tid = blockIdx.x * blockDim.x + threadIdx.x;
    int node = tid >> 5;
    int f = tid & 31;
    if (node >= n) return;
    float4 pd = params[node];
    int beg = row_ptr[node], end = row_ptr[node + 1];
    float acc = 0.0f;
    bool lo = (f < 16);
    for (int p = beg; p < end; ++p) {
        int s = csr_src[p];
        float4 ps = params[s];
        float cd = pd.x * ps.x + pd.y * ps.y;   // cos(th_s - th_d)
        float sd = ps.y * pd.x - ps.x * pd.y;   // sin(th_s - th_d)
        float nrm = ps.z * pd.z;
        float x_own = xs[(size_t)s * 32 + f];
        float x_part = __shfl_xor(x_own, 16, 64);
        float val = lo ? (cd * x_own - sd * x_part) : (sd * x_part + cd * x_own);
        acc += nrm * val;
    }
    aggx[(size_t)node * 32 + f] = acc;
}

// xs = xs - gelu((xs - aggx) @ Wd)
__global__ void k_update(float* __restrict__ xs, const float* __restrict__ aggx,
                         const float* __restrict__ Wd, int n) {
    __shared__ float sW[256];
    for (int i = threadIdx.x; i < 256; i += blockDim.x) sW[i] = Wd[i];
    __syncthreads();
    int node = blockIdx.x * blockDim.x + threadIdx.x;
    if (node >= n) return;
    float xr[32], lx[32];
    float* xrow = xs + (size_t)node * 32;
    const float* arow = aggx + (size_t)node * 32;
#pragma unroll
    for (int i = 0; i < 32; i++) {
        xr[i] = xrow[i];
        lx[i] = xr[i] - arow[i];
    }
#pragma unroll
    for (int dd = 0; dd < 2; dd++) {
        for (int j = 0; j < 16; j++) {
            float acc = 0.0f;
#pragma unroll
            for (int k = 0; k < 16; k++) acc += lx[dd * 16 + k] * sW[k * 16 + j];
            xrow[dd * 16 + j] = xr[dd * 16 + j] - gelu_tanh(acc);
        }
    }
}

__global__ void k_out(const float* __restrict__ xs, const float* __restrict__ W,
                      const float* __restrict__ b, float* __restrict__ out, int n) {
    __shared__ float sW[320];
    __shared__ float sb[10];
    for (int i = threadIdx.x; i < 320; i += blockDim.x) sW[i] = W[i];
    for (int i = threadIdx.x; i < 10; i += blockDim.x) sb[i] = b[i];
    __syncthreads();
    int node = blockIdx.x * blockDim.x + threadIdx.x;
    if (node >= n) return;
    float xr[32];
    const float4* x4 = (const float4*)(xs + (size_t)node * 32);
#pragma unroll
    for (int i = 0; i < 8; i++) {
        float4 v = x4[i];
        xr[4 * i] = v.x; xr[4 * i + 1] = v.y; xr[4 * i + 2] = v.z; xr[4 * i + 3] = v.w;
    }
    float* orow = out + (size_t)node * 10;
#pragma unroll
    for (int j = 0; j < 10; j++) {
        float acc = sb[j];
#pragma unroll
        for (int k = 0; k < 32; k++) acc += xr[k] * sW[k * 10 + j];
        orow[j] = acc;
    }
}

static inline size_t align256(size_t x) { return (x + 255) & ~(size_t)255; }

extern "C" void kernel_launch(void* const* d_in, const int* in_sizes, int n_in,
                              void* d_out, int out_size, void* d_ws, size_t ws_size,
                              hipStream_t stream) {
    const float* x      = (const float*)d_in[0];
    const int*   ei     = (const int*)d_in[1];
    const float* W_in   = (const float*)d_in[2];
    const float* b_in   = (const float*)d_in[3];
    const float* emb1_W = (const float*)d_in[4];
    const float* emb1_b = (const float*)d_in[5];
    const float* Ws1    = (const float*)d_in[6];
    const float* Wn1    = (const float*)d_in[7];
    const float* Ws2    = (const float*)d_in[8];
    const float* Wn2    = (const float*)d_in[9];
    const float* emb2_W = (const float*)d_in[10];
    const float* emb2_b = (const float*)d_in[11];
    const float* W_diff = (const float*)d_in[12];
    const float* W_out  = (const float*)d_in[13];
    const float* b_out  = (const float*)d_in[14];

    int n = in_sizes[0] / 128;  // 100000
    int e = in_sizes[1] / 2;    // 1600000
    int nt = (n + 255) / 256;   // scan tiles (<=1024 supported)

    // ---- workspace layout (256B-aligned sections) ----
    char* base = (char*)d_ws;
    size_t off = 0;
    int* src      = (int*)(base + off); off = align256(off + (size_t)e * 4);
    int* dst      = (int*)(base + off); off = align256(off + (size_t)e * 4);
    int* csr_src  = (int*)(base + off); off = align256(off + (size_t)e * 4);
    int* row_ptr  = (int*)(base + off); off = align256(off + (size_t)(n + 1) * 4);
    int* cursor   = (int*)(base + off); off = align256(off + (size_t)n * 4);
    int* bsums    = (int*)(base + off); off = align256(off + (size_t)nt * 4);
    int* flag     = (int*)(base + off); off = align256(off + 16);
    float*  h     = (float*)(base + off); off = align256(off + (size_t)n * 32 * 4);
    float*  m     = (float*)(base + off); off = align256(off + (size_t)n * 64 * 4);
    float*  agg   = (float*)(base + off); off = align256(off + (size_t)n * 64 * 4);
    float4* params= (float4*)(base + off);

    int nb = (n + 255) / 256;
    int eb = (e + 255) / 256;

    // edge convert + CSR build
    k_detect<<<1, 64, 0, stream>>>(ei, flag);
    k_convert<<<eb, 256, 0, stream>>>(ei, flag, src, dst, e);
    hipMemsetAsync(cursor, 0, (size_t)n * 4, stream);
    k_hist<<<eb, 256, 0, stream>>>(dst, cursor, e);
    k_scan1<<<nt, 256, 0, stream>>>(cursor, row_ptr, bsums, n);
    k_scan2<<<1, 1024, 0, stream>>>(bsums, nt);
    k_scan3<<<nt, 256, 0, stream>>>(row_ptr, bsums, n);
    k_copy<<<nb, 256, 0, stream>>>(row_ptr, cursor, n);
    k_fill<<<eb, 256, 0, stream>>>(src, dst, cursor, csr_src, e);

    // embeddings
    k_embed_h<<<nb, 256, 0, stream>>>(x, W_in, b_in, h, n);
    k_embed_m<<<nb, 256, 0, stream>>>(h, emb1_W, emb1_b, m, n);

    // sheaf learner GNN layers (gather + tiled dense)
    int gb64 = (n * 64 + 255) / 256;
    int gnb  = (n + 63) / 64;            // 64 nodes per block
    k_gather64<<<gb64, 256, 0, stream>>>(row_ptr, csr_src, m, agg, n);
    k_gnn<<<gnb, 256, 0, stream>>>(m, agg, Ws1, Wn1, m, n);
    k_gather64<<<gb64, 256, 0, stream>>>(row_ptr, csr_src, m, agg, n);
    k_gnn<<<gnb, 256, 0, stream>>>(m, agg, Ws2, Wn2, m, n);

    k_params<<<nb, 256, 0, stream>>>(m, emb2_W, emb2_b, row_ptr, params, n);

    // diffusion layers (gather + update)
    int gb32 = (n * 32 + 255) / 256;
    for (int l = 0; l < 2; l++) {
        k_gather_diffuse<<<gb32, 256, 0, stream>>>(row_ptr, csr_src, h, params, agg, n);
        k_update<<<nb, 256, 0, stream>>>(h, agg, W_diff + (size_t)l * 256, n);
    }

    k_out<<<nb, 256, 0, stream>>>(h, W_out, b_out, (float*)d_out, n);
}

// Round 7
// 879.319 us; speedup vs baseline: 2.3482x; 1.2835x over previous
//
#include <hip/hip_runtime.h>
#include <math.h>

// ---------------------------------------------------------------------------
// SheafDiffusion on MI355X — round 6: kill scratch spills in k_embed_m /
// k_embed_h (register-tiled GEMMs, 4x4 / 2x4 acc per thread) and k_update
// (process stalk halves independently; matmul is block-diagonal in d).
// ---------------------------------------------------------------------------

__device__ __forceinline__ float gelu_tanh(float x) {
    float x3 = x * x * x;
    float t = tanhf(0.7978845608028654f * (x + 0.044715f * x3));
    return 0.5f * x * (1.0f + t);
}

// ---- edge dtype handling -------------------------------------------------
__global__ void k_detect(const int* __restrict__ ei, int* __restrict__ flag) {
    if (blockIdx.x == 0 && threadIdx.x == 0) {
        int is64 = 1;
        for (int i = 1; i < 256; i += 2)
            if (ei[i] != 0) { is64 = 0; break; }
        *flag = is64;
    }
}

__global__ void k_convert(const int* __restrict__ ei, const int* __restrict__ flag,
                          int* __restrict__ src, int* __restrict__ dst, int e) {
    int i = blockIdx.x * blockDim.x + threadIdx.x;
    if (i >= e) return;
    if (*flag) {
        src[i] = ei[2 * i];
        dst[i] = ei[2 * (e + i)];
    } else {
        src[i] = ei[i];
        dst[i] = ei[e + i];
    }
}

// ---- CSR build -----------------------------------------------------------
__global__ void k_hist(const int* __restrict__ dst, int* __restrict__ cnt, int e) {
    int i = blockIdx.x * blockDim.x + threadIdx.x;
    if (i < e) atomicAdd(&cnt[dst[i]], 1);
}

__global__ void k_scan1(const int* __restrict__ cnt, int* __restrict__ row_ptr,
                        int* __restrict__ bs, int n) {
    __shared__ int s[256];
    int i = blockIdx.x * 256 + threadIdx.x;
    int v = (i < n) ? cnt[i] : 0;
    s[threadIdx.x] = v;
    __syncthreads();
#pragma unroll
    for (int off = 1; off < 256; off <<= 1) {
        int add = (threadIdx.x >= off) ? s[threadIdx.x - off] : 0;
        __syncthreads();
        s[threadIdx.x] += add;
        __syncthreads();
    }
    if (i < n) row_ptr[i + 1] = s[threadIdx.x];
    if (threadIdx.x == 255) bs[blockIdx.x] = s[255];
}

__global__ void k_scan2(int* __restrict__ bs, int nt) {
    __shared__ int s[1024];
    int t = threadIdx.x;
    s[t] = (t < nt) ? bs[t] : 0;
    __syncthreads();
#pragma unroll
    for (int off = 1; off < 1024; off <<= 1) {
        int add = (t >= off) ? s[t - off] : 0;
        __syncthreads();
        s[t] += add;
        __syncthreads();
    }
    if (t < nt) bs[t] = (t == 0) ? 0 : s[t - 1];
}

__global__ void k_scan3(int* __restrict__ row_ptr, const int* __restrict__ bs, int n) {
    int i = blockIdx.x * 256 + threadIdx.x;
    if (i < n) row_ptr[i + 1] += bs[blockIdx.x];
    if (i == 0) row_ptr[0] = 0;
}

__global__ void k_copy(const int* __restrict__ row_ptr, int* __restrict__ cursor, int n) {
    int i = blockIdx.x * blockDim.x + threadIdx.x;
    if (i < n) cursor[i] = row_ptr[i];
}

__global__ void k_fill(const int* __restrict__ src, const int* __restrict__ dst,
                       int* __restrict__ cursor, int* __restrict__ csr_src, int e) {
    int i = blockIdx.x * blockDim.x + threadIdx.x;
    if (i >= e) return;
    int d = dst[i];
    int pos = atomicAdd(&cursor[d], 1);
    csr_src[pos] = src[i];
}

// ---- tiled dense kernels -------------------------------------------------
// h = x @ W_in + b_in   (N,128)@(128,32) — tile: 64 nodes x 32 feats, K=128.
// Thread (tx 0..7, ty 0..31): 4 feats x 2 nodes; acc[2][4].
__global__ __launch_bounds__(256) void k_embed_h(const float* __restrict__ x,
                          const float* __restrict__ W_in, const float* __restrict__ b_in,
                          float* __restrict__ h, int n) {
    __shared__ float sW[128 * 32];     // 16 KB
    __shared__ float sX[128 * 68];     // 34.8 KB, transposed [k][node], pad 68
    __shared__ float sb[32];
    int tid = threadIdx.x;
    for (int i = tid; i < 128 * 32; i += 256) sW[i] = W_in[i];
    for (int i = tid; i < 32; i += 256) sb[i] = b_in[i];

    int node0 = blockIdx.x * 64;
    int r = tid >> 2;         // row 0..63
    int q0 = tid & 3;
    int node_r = node0 + r;
    const float4* xrow = (const float4*)(x + (size_t)node_r * 128);
#pragma unroll
    for (int qq = 0; qq < 8; qq++) {
        int q = qq * 4 + q0;  // quad 0..31 -> k = q*4..q*4+3
        float4 v = (node_r < n) ? xrow[q] : make_float4(0.f, 0.f, 0.f, 0.f);
        sX[(q * 4 + 0) * 68 + r] = v.x;
        sX[(q * 4 + 1) * 68 + r] = v.y;
        sX[(q * 4 + 2) * 68 + r] = v.z;
        sX[(q * 4 + 3) * 68 + r] = v.w;
    }
    __syncthreads();

    int tx = tid & 7;         // feature quad (8*4 = 32 feats)
    int ty = tid >> 3;        // node pair (32*2 = 64 nodes)
    float acc[2][4];
#pragma unroll
    for (int i = 0; i < 2; i++)
#pragma unroll
        for (int j = 0; j < 4; j++) acc[i][j] = 0.0f;

#pragma unroll 4
    for (int k = 0; k < 128; k++) {
        float a0 = sX[k * 68 + ty * 2];
        float a1 = sX[k * 68 + ty * 2 + 1];
        float4 wv = *(const float4*)&sW[k * 32 + tx * 4];
#pragma unroll
        for (int j = 0; j < 4; j++) {
            float w = (&wv.x)[j];
            acc[0][j] += a0 * w;
            acc[1][j] += a1 * w;
        }
    }
    float4 bias = make_float4(sb[tx * 4], sb[tx * 4 + 1], sb[tx * 4 + 2], sb[tx * 4 + 3]);
#pragma unroll
    for (int i = 0; i < 2; i++) {
        int node = node0 + ty * 2 + i;
        if (node >= n) continue;
        float4 o;
        o.x = acc[i][0] + bias.x;
        o.y = acc[i][1] + bias.y;
        o.z = acc[i][2] + bias.z;
        o.w = acc[i][3] + bias.w;
        *(float4*)&h[(size_t)node * 32 + tx * 4] = o;
    }
}

// m = gelu(h @ emb1_W + emb1_b)  (N,32)@(32,64) — tile: 64 nodes x 64 feats.
// Thread (tx 0..15, ty 0..3): 4 feats x 4 nodes; acc[4][4].
__global__ __launch_bounds__(256) void k_embed_m(const float* __restrict__ h,
                          const float* __restrict__ W, const float* __restrict__ b,
                          float* __restrict__ m, int n) {
    __shared__ float sW[32 * 64];     // 8 KB
    __shared__ float sA[32 * 68];     // 8.7 KB, transposed [k][node]
    __shared__ float sb[64];
    int tid = threadIdx.x;
    for (int i = tid; i < 32 * 64; i += 256) sW[i] = W[i];
    for (int i = tid; i < 64; i += 256) sb[i] = b[i];

    int node0 = blockIdx.x * 64;
    int r = tid >> 2;
    int q0 = tid & 3;
    int node_r = node0 + r;
    const float4* hrow = (const float4*)(h + (size_t)node_r * 32);
#pragma unroll
    for (int qq = 0; qq < 2; qq++) {
        int q = qq * 4 + q0;  // quad 0..7 -> k = q*4..q*4+3
        float4 v = (node_r < n) ? hrow[q] : make_float4(0.f, 0.f, 0.f, 0.f);
        sA[(q * 4 + 0) * 68 + r] = v.x;
        sA[(q * 4 + 1) * 68 + r] = v.y;
        sA[(q * 4 + 2) * 68 + r] = v.z;
        sA[(q * 4 + 3) * 68 + r] = v.w;
    }
    __syncthreads();

    int tx = tid & 15;
    int ty = tid >> 4;
    float acc[4][4];
#pragma unroll
    for (int i = 0; i < 4; i++)
#pragma unroll
        for (int j = 0; j < 4; j++) acc[i][j] = 0.0f;

#pragma unroll 4
    for (int k = 0; k < 32; k++) {
        float4 av = *(const float4*)&sA[k * 68 + ty * 4];
        float4 wv = *(const float4*)&sW[k * 64 + tx * 4];
        float a_[4] = {av.x, av.y, av.z, av.w};
#pragma unroll
        for (int i = 0; i < 4; i++)
#pragma unroll
            for (int j = 0; j < 4; j++)
                acc[i][j] += a_[i] * (&wv.x)[j];
    }
    float4 bias = make_float4(sb[tx * 4], sb[tx * 4 + 1], sb[tx * 4 + 2], sb[tx * 4 + 3]);
#pragma unroll
    for (int i = 0; i < 4; i++) {
        int node = node0 + ty * 4 + i;
        if (node >= n) continue;
        float4 o;
        o.x = gelu_tanh(acc[i][0] + bias.x);
        o.y = gelu_tanh(acc[i][1] + bias.y);
        o.z = gelu_tanh(acc[i][2] + bias.z);
        o.w = gelu_tanh(acc[i][3] + bias.w);
        *(float4*)&m[(size_t)node * 64 + tx * 4] = o;
    }
}

// agg[node] = sum over in-edges of m[src]   (one wave per node, 64 lanes = feats)
__global__ void k_gather64(const int* __restrict__ row_ptr, const int* __restrict__ csr_src,
                           const float* __restrict__ m, float* __restrict__ agg, int n) {
    int wave = (blockIdx.x * blockDim.x + threadIdx.x) >> 6;
    int f = threadIdx.x & 63;
    if (wave >= n) return;
    int beg = row_ptr[wave], end = row_ptr[wave + 1];
    float acc = 0.0f;
    int p = beg;
    for (; p + 1 < end; p += 2) {
        int s0 = csr_src[p], s1 = csr_src[p + 1];
        float a = m[(size_t)s0 * 64 + f];
        float b = m[(size_t)s1 * 64 + f];
        acc += a + b;
    }
    if (p < end) acc += m[(size_t)csr_src[p] * 64 + f];
    agg[(size_t)wave * 64 + f] = acc;
}

// m_out = gelu(m_in @ Ws + agg @ Wn) — register-tiled GEMM (round-5 version).
__global__ __launch_bounds__(256) void k_gnn(const float* m_in, const float* __restrict__ agg,
                      const float* __restrict__ Ws, const float* __restrict__ Wn,
                      float* m_out, int n) {
    __shared__ float sWs[64 * 64];
    __shared__ float sWn[64 * 64];
    __shared__ float sA[64 * 68];
    int tid = threadIdx.x;
    for (int i = tid; i < 64 * 64; i += 256) { sWs[i] = Ws[i]; sWn[i] = Wn[i]; }
    int node0 = blockIdx.x * 64;
    int tx = tid & 15;
    int ty = tid >> 4;
    float acc[4][4];
#pragma unroll
    for (int i = 0; i < 4; i++)
#pragma unroll
        for (int j = 0; j < 4; j++) acc[i][j] = 0.0f;

#pragma unroll
    for (int phase = 0; phase < 2; phase++) {
        const float* A = phase ? agg : m_in;
        __syncthreads();
        int r0 = tid >> 6;
        int c = tid & 63;
#pragma unroll
        for (int rr = 0; rr < 16; rr++) {
            int r = rr * 4 + r0;
            int node = node0 + r;
            float v = (node < n) ? A[(size_t)node * 64 + c] : 0.0f;
            sA[c * 68 + r] = v;
        }
        __syncthreads();
        const float* w = phase ? sWn : sWs;
#pragma unroll 4
        for (int k = 0; k < 64; k++) {
            float4 av = *(const float4*)&sA[k * 68 + ty * 4];
            float4 wv = *(const float4*)&w[k * 64 + tx * 4];
            float a_[4] = {av.x, av.y, av.z, av.w};
#pragma unroll
            for (int i = 0; i < 4; i++)
#pragma unroll
                for (int j = 0; j < 4; j++)
                    acc[i][j] += a_[i] * (&wv.x)[j];
        }
    }
#pragma unroll
    for (int i = 0; i < 4; i++) {
        int node = node0 + ty * 4 + i;
        if (node >= n) continue;
        float4 o;
        o.x = gelu_tanh(acc[i][0]);
        o.y = gelu_tanh(acc[i][1]);
        o.z = gelu_tanh(acc[i][2]);
        o.w = gelu_tanh(acc[i][3]);
        *(float4*)&m_out[(size_t)node * 64 + tx * 4] = o;
    }
}

// theta -> per-node (cos, sin, rsqrt(deg+1), 0)
__global__ void k_params(const float* __restrict__ m, const float* __restrict__ w2,
                         const float* __restrict__ b2, const int* __restrict__ row_ptr,
                         float4* __restrict__ params, int n) {
    __shared__ float sw[64];
    for (int i = threadIdx.x; i < 64; i += blockDim.x) sw[i] = w2[i];
    __syncthreads();
    int node = blockIdx.x * blockDim.x + threadIdx.x;
    if (node >= n) return;
    float acc = b2[0];
    const float* mr = m + (size_t)node * 64;
#pragma unroll
    for (int k = 0; k < 64; k++) acc += mr[k] * sw[k];
    float theta = tanhf(acc);
    float ang = 6.283185307179586f * theta;
    float c = cosf(ang), s = sinf(ang);
    float deg = (float)(row_ptr[node + 1] - row_ptr[node]);
    float rd = rsqrtf(deg + 1.0f);
    params[node] = make_float4(c, s, rd, 0.0f);
}

// aggx[node] = sum_e norm_e * R(th_s - th_d) @ xs[src]   (32 lanes per node)
__global__ void k_gather_diffuse(const int* __restrict__ row_ptr, const int* __restrict__ csr_src,
                                 const float* __restrict__ xs, const float4* __restrict__ params,
                                 float* __restrict__ aggx, int n) {
    int tid = blockIdx.x * blockDim.x + threadIdx.x;
    int node = tid >> 5;
    int f = tid & 31;
    if (node >= n) return;
    float4 pd = params[node];
    int beg = row_ptr[node], end = row_ptr[node + 1];
    float acc = 0.0f;
    bool lo = (f < 16);
    for (int p = beg; p < end; ++p) {
        int s = csr_src[p];
        float4 ps = params[s];
        float cd = pd.x * ps.x + pd.y * ps.y;
        float sd = ps.y * pd.x - ps.x * pd.y;
        float nrm = ps.z * pd.z;
        float x_own = xs[(size_t)s * 32 + f];
        float x_part = __shfl_xor(x_own, 16, 64);
        float val = lo ? (cd * x_own - sd * x_part) : (sd * x_part + cd * x_own);
        acc += nrm * val;
    }
    aggx[(size_t)node * 32 + f] = acc;
}

// xs = xs - gelu((xs - aggx) @ Wd); W is block-diagonal in d -> per-half.
__global__ void k_update(float* __restrict__ xs, const float* __restrict__ aggx,
                         const float* __restrict__ Wd, int n) {
    __shared__ float sW[256];
    for (int i = threadIdx.x; i < 256; i += blockDim.x) sW[i] = Wd[i];
    __syncthreads();
    int node = blockIdx.x * blockDim.x + threadIdx.x;
    if (node >= n) return;
    float* xrow = xs + (size_t)node * 32;
    const float* arow = aggx + (size_t)node * 32;
#pragma unroll
    for (int dd = 0; dd < 2; dd++) {
        float xr[16], lx[16];
        const float4* x4 = (const float4*)(xrow + dd * 16);
        const float4* a4 = (const float4*)(arow + dd * 16);
#pragma unroll
        for (int i = 0; i < 4; i++) {
            float4 v = x4[i], a = a4[i];
            xr[4 * i] = v.x; xr[4 * i + 1] = v.y; xr[4 * i + 2] = v.z; xr[4 * i + 3] = v.w;
            lx[4 * i] = v.x - a.x; lx[4 * i + 1] = v.y - a.y;
            lx[4 * i + 2] = v.z - a.z; lx[4 * i + 3] = v.w - a.w;
        }
        float4* xo = (float4*)(xrow + dd * 16);
#pragma unroll
        for (int jq = 0; jq < 4; jq++) {
            float o[4];
#pragma unroll
            for (int jj = 0; jj < 4; jj++) {
                int j = jq * 4 + jj;
                float acc = 0.0f;
#pragma unroll
                for (int k = 0; k < 16; k++) acc += lx[k] * sW[k * 16 + j];
                o[jj] = xr[j] - gelu_tanh(acc);
            }
            xo[jq] = make_float4(o[0], o[1], o[2], o[3]);
        }
    }
}

__global__ void k_out(const float* __restrict__ xs, const float* __restrict__ W,
                      const float* __restrict__ b, float* __restrict__ out, int n) {
    __shared__ float sW[320];
    __shared__ float sb[10];
    for (int i = threadIdx.x; i < 320; i += blockDim.x) sW[i] = W[i];
    for (int i = threadIdx.x; i < 10; i += blockDim.x) sb[i] = b[i];
    __syncthreads();
    int node = blockIdx.x * blockDim.x + threadIdx.x;
    if (node >= n) return;
    float xr[32];
    const float4* x4 = (const float4*)(xs + (size_t)node * 32);
#pragma unroll
    for (int i = 0; i < 8; i++) {
        float4 v = x4[i];
        xr[4 * i] = v.x; xr[4 * i + 1] = v.y; xr[4 * i + 2] = v.z; xr[4 * i + 3] = v.w;
    }
    float* orow = out + (size_t)node * 10;
#pragma unroll
    for (int j = 0; j < 10; j++) {
        float acc = sb[j];
#pragma unroll
        for (int k = 0; k < 32; k++) acc += xr[k] * sW[k * 10 + j];
        orow[j] = acc;
    }
}

static inline size_t align256(size_t x) { return (x + 255) & ~(size_t)255; }

extern "C" void kernel_launch(void* const* d_in, const int* in_sizes, int n_in,
                              void* d_out, int out_size, void* d_ws, size_t ws_size,
                              hipStream_t stream) {
    const float* x      = (const float*)d_in[0];
    const int*   ei     = (const int*)d_in[1];
    const float* W_in   = (const float*)d_in[2];
    const float* b_in   = (const float*)d_in[3];
    const float* emb1_W = (const float*)d_in[4];
    const float* emb1_b = (const float*)d_in[5];
    const float* Ws1    = (const float*)d_in[6];
    const float* Wn1    = (const float*)d_in[7];
    const float* Ws2    = (const float*)d_in[8];
    const float* Wn2    = (const float*)d_in[9];
    const float* emb2_W = (const float*)d_in[10];
    const float* emb2_b = (const float*)d_in[11];
    const float* W_diff = (const float*)d_in[12];
    const float* W_out  = (const float*)d_in[13];
    const float* b_out  = (const float*)d_in[14];

    int n = in_sizes[0] / 128;  // 100000
    int e = in_sizes[1] / 2;    // 1600000
    int nt = (n + 255) / 256;

    char* base = (char*)d_ws;
    size_t off = 0;
    int* src      = (int*)(base + off); off = align256(off + (size_t)e * 4);
    int* dst      = (int*)(base + off); off = align256(off + (size_t)e * 4);
    int* csr_src  = (int*)(base + off); off = align256(off + (size_t)(n + 1) * 4 + (size_t)e * 4) - align256((size_t)(n + 1) * 4);
    // (csr_src sized e ints; recompute offsets cleanly below instead)
    off = 0;
    src      = (int*)(base + off); off = align256(off + (size_t)e * 4);
    dst      = (int*)(base + off); off = align256(off + (size_t)e * 4);
    csr_src  = (int*)(base + off); off = align256(off + (size_t)e * 4);
    int* row_ptr  = (int*)(base + off); off = align256(off + (size_t)(n + 1) * 4);
    int* cursor   = (int*)(base + off); off = align256(off + (size_t)n * 4);
    int* bsums    = (int*)(base + off); off = align256(off + (size_t)nt * 4);
    int* flag     = (int*)(base + off); off = align256(off + 16);
    float*  h     = (float*)(base + off); off = align256(off + (size_t)n * 32 * 4);
    float*  m     = (float*)(base + off); off = align256(off + (size_t)n * 64 * 4);
    float*  agg   = (float*)(base + off); off = align256(off + (size_t)n * 64 * 4);
    float4* params= (float4*)(base + off);

    int nb = (n + 255) / 256;
    int eb = (e + 255) / 256;
    int tb64 = (n + 63) / 64;   // 64-node tiles

    k_detect<<<1, 64, 0, stream>>>(ei, flag);
    k_convert<<<eb, 256, 0, stream>>>(ei, flag, src, dst, e);
    hipMemsetAsync(cursor, 0, (size_t)n * 4, stream);
    k_hist<<<eb, 256, 0, stream>>>(dst, cursor, e);
    k_scan1<<<nt, 256, 0, stream>>>(cursor, row_ptr, bsums, n);
    k_scan2<<<1, 1024, 0, stream>>>(bsums, nt);
    k_scan3<<<nt, 256, 0, stream>>>(row_ptr, bsums, n);
    k_copy<<<nb, 256, 0, stream>>>(row_ptr, cursor, n);
    k_fill<<<eb, 256, 0, stream>>>(src, dst, cursor, csr_src, e);

    k_embed_h<<<tb64, 256, 0, stream>>>(x, W_in, b_in, h, n);
    k_embed_m<<<tb64, 256, 0, stream>>>(h, emb1_W, emb1_b, m, n);

    int gb64 = (n * 64 + 255) / 256;
    k_gather64<<<gb64, 256, 0, stream>>>(row_ptr, csr_src, m, agg, n);
    k_gnn<<<tb64, 256, 0, stream>>>(m, agg, Ws1, Wn1, m, n);
    k_gather64<<<gb64, 256, 0, stream>>>(row_ptr, csr_src, m, agg, n);
    k_gnn<<<tb64, 256, 0, stream>>>(m, agg, Ws2, Wn2, m, n);

    k_params<<<nb, 256, 0, stream>>>(m, emb2_W, emb2_b, row_ptr, params, n);

    int gb32 = (n * 32 + 255) / 256;
    for (int l = 0; l < 2; l++) {
        k_gather_diffuse<<<gb32, 256, 0, stream>>>(row_ptr, csr_src, h, params, agg, n);
        k_update<<<nb, 256, 0, stream>>>(h, agg, W_diff + (size_t)l * 256, n);
    }

    k_out<<<nb, 256, 0, stream>>>(h, W_out, b_out, (float*)d_out, n);
}